// Round 9
// baseline (1905.575 us; speedup 1.0000x reference)
//
#include <hip/hip_runtime.h>

#define Bdim 8
#define Nn 200
#define NDd 128
#define Hd 256
#define FFd 1024
#define Ld 3
#define NHh 8
#define DHd 32
#define Mtot (Bdim * Nn)  // 1600
#define ZS 409600         // partial stride (Mtot*Hd)
#define GRD 400           // mega-kernel grid (co-resident: <=2 blocks/CU ok)
#define NBAR 24

typedef unsigned short u16;
typedef unsigned int u32;
using short8 = __attribute__((ext_vector_type(8))) short;
using fx4 = __attribute__((ext_vector_type(4))) float;

__device__ __forceinline__ float siluf(float x) {
  return x * __builtin_amdgcn_rcpf(1.0f + __expf(-x));
}

__device__ __forceinline__ void bsplit(float x, u16& h, u16& l) {
  u32 b = __float_as_uint(x);
  h = (u16)(b >> 16);
  float hf = __uint_as_float(b & 0xffff0000u);
  float r = x - hf;
  l = (u16)(__float_as_uint(r) >> 16);
}

__device__ __forceinline__ void store_xfrag(u16* __restrict__ xh,
                                            u16* __restrict__ xl, int m, int c,
                                            float v) {
  u32 o = ((u32)((m >> 4) * 8 + (c >> 5)) * 64 + ((c & 31) >> 3) * 16 +
           (m & 15)) * 8 + (c & 7);
  u16 hh, ll;
  bsplit(v, hh, ll);
  xh[o] = hh;
  xl[o] = ll;
}

// grid barrier: fresh counter per sync point (zeroed by memset each launch)
__device__ __forceinline__ void gbar(int* bar, int idx) {
  __syncthreads();
  if (threadIdx.x == 0) {
    __threadfence();
    __hip_atomic_fetch_add(bar + idx, 1, __ATOMIC_ACQ_REL,
                           __HIP_MEMORY_SCOPE_AGENT);
    while (__hip_atomic_load(bar + idx, __ATOMIC_ACQUIRE,
                             __HIP_MEMORY_SCOPE_AGENT) < GRD) {
      __builtin_amdgcn_s_sleep(2);
    }
  }
  __syncthreads();
}

struct SplitDesc {
  const float* s;
  u32 off;  // ushort offset into WH/WL (multiple of 8)
  int K, N;
};
struct SplitArgs {
  SplitDesc d[14];
  int pre[15];  // prefix sums of per-desc short8 item counts
};

// bf16x3 MFMA GEMM tile (prefetch, optional k-split / relu-frag / merge)
template <int KSZ, int EPI, int MERGE>
__device__ __forceinline__ void gemm_tile(
    int bx, int by, int bz, int lane, int wv,
    const u16* __restrict__ ah, const u16* __restrict__ al,
    const float* __restrict__ pO, const float* __restrict__ pl,
    const u16* __restrict__ wh, const u16* __restrict__ wl,
    const float* __restrict__ bias, float* __restrict__ outf,
    u16* __restrict__ oh, u16* __restrict__ ol, int N, int KS,
    size_t zstride) {
  int rt = bx * 4 + wv;
  int nt0 = by * 4;
  int ks0 = bz * KSZ;
  int m16 = lane & 15, quad = lane >> 4;
  int mrow = rt * 16 + m16;
  int bq = mrow / Nn, iq = mrow % Nn;  // merge path
  fx4 z4 = {0.f, 0.f, 0.f, 0.f};
  fx4 acc[4] = {z4, z4, z4, z4};
  const short8* pah = (const short8*)ah;
  const short8* pal = (const short8*)al;
  const short8* pwh = (const short8*)wh;
  const short8* pwl = (const short8*)wl;

  auto loadA = [&](int ks, short8& a_h, short8& a_l) {
    if (MERGE) {
      int head = ks0 + ks;
      float o8[8];
      float denom = 0.f;
#pragma unroll
      for (int z = 0; z < 4; ++z) {
        int base = ((bq * NHh + head) * 4 + z) * Nn + iq;
        denom += pl[base];
        const float* p = pO + (size_t)base * 32 + quad * 8;
        float4 v0 = *(const float4*)p;
        float4 v1 = *(const float4*)(p + 4);
        if (z == 0) {
          o8[0] = v0.x; o8[1] = v0.y; o8[2] = v0.z; o8[3] = v0.w;
          o8[4] = v1.x; o8[5] = v1.y; o8[6] = v1.z; o8[7] = v1.w;
        } else {
          o8[0] += v0.x; o8[1] += v0.y; o8[2] += v0.z; o8[3] += v0.w;
          o8[4] += v1.x; o8[5] += v1.y; o8[6] += v1.z; o8[7] += v1.w;
        }
      }
      float rd = 1.0f / denom;
#pragma unroll
      for (int e = 0; e < 8; ++e) {
        u16 hh, ll;
        bsplit(o8[e] * rd, hh, ll);
        a_h[e] = (short)hh;
        a_l[e] = (short)ll;
      }
    } else {
      a_h = pah[(size_t)(rt * KS + ks0 + ks) * 64 + lane];
      a_l = pal[(size_t)(rt * KS + ks0 + ks) * 64 + lane];
    }
  };

  short8 ca_h, ca_l, cb_h[4], cb_l[4];
  loadA(0, ca_h, ca_l);
#pragma unroll
  for (int nt = 0; nt < 4; ++nt) {
    size_t wi = ((size_t)(nt0 + nt) * KS + ks0) * 64 + lane;
    cb_h[nt] = pwh[wi];
    cb_l[nt] = pwl[wi];
  }
#pragma unroll
  for (int ks = 0; ks < KSZ; ++ks) {
    short8 na_h, na_l, nb_h[4], nb_l[4];
    if (ks + 1 < KSZ) {
      loadA(ks + 1, na_h, na_l);
#pragma unroll
      for (int nt = 0; nt < 4; ++nt) {
        size_t wi = ((size_t)(nt0 + nt) * KS + ks0 + ks + 1) * 64 + lane;
        nb_h[nt] = pwh[wi];
        nb_l[nt] = pwl[wi];
      }
    }
#pragma unroll
    for (int nt = 0; nt < 4; ++nt) {
      acc[nt] = __builtin_amdgcn_mfma_f32_16x16x32_bf16(ca_h, cb_h[nt], acc[nt], 0, 0, 0);
      acc[nt] = __builtin_amdgcn_mfma_f32_16x16x32_bf16(ca_h, cb_l[nt], acc[nt], 0, 0, 0);
      acc[nt] = __builtin_amdgcn_mfma_f32_16x16x32_bf16(ca_l, cb_h[nt], acc[nt], 0, 0, 0);
    }
    ca_h = na_h;
    ca_l = na_l;
#pragma unroll
    for (int nt = 0; nt < 4; ++nt) {
      cb_h[nt] = nb_h[nt];
      cb_l[nt] = nb_l[nt];
    }
  }

  size_t zoff = (size_t)bz * zstride;
#pragma unroll
  for (int nt = 0; nt < 4; ++nt) {
    int col = (nt0 + nt) * 16 + m16;
    float bv = (bias && bz == 0) ? bias[col] : 0.f;
#pragma unroll
    for (int r = 0; r < 4; ++r) {
      int row = rt * 16 + quad * 4 + r;
      float v = acc[nt][r] + bv;
      if (EPI == 0) {
        outf[zoff + (size_t)row * N + col] = v;
      } else {
        v = fmaxf(v, 0.f);
        u32 o = ((u32)(rt * 32 + (col >> 5)) * 64 + ((col & 31) >> 3) * 16 +
                 (row & 15)) * 8 + (col & 7);
        u16 hh, ll;
        bsplit(v, hh, ll);
        oh[o] = hh;
        ol[o] = ll;
      }
    }
  }
}

__global__ __launch_bounds__(256, 2) void mega_kernel(
    SplitArgs sa, float* __restrict__ ws, const float* __restrict__ hin,
    const float* __restrict__ xt, const float* __restrict__ t,
    const float* __restrict__ tw1, const float* __restrict__ tb1,
    const float* __restrict__ tw2, const float* __restrict__ tb2,
    const float* __restrict__ ew, const float* __restrict__ eb,
    const float* __restrict__ pw, const float* __restrict__ pb,
    const float* __restrict__ qkv_b, const float* __restrict__ ao_b,
    const float* __restrict__ ln1_g, const float* __restrict__ ln1_b,
    const float* __restrict__ f1_b, const float* __restrict__ f2_b,
    const float* __restrict__ ln2_g, const float* __restrict__ ln2_b,
    const float* __restrict__ ow1, const float* __restrict__ ob1,
    const float* __restrict__ ow2, const float* __restrict__ ob2,
    float* __restrict__ out) {
  // workspace layout (floats), proven in round 8
  float* temb = ws;
  float* u    = ws + 2048;
  float* w0   = ws + 2304;
  float* x    = ws + 4096;
  u16*   x_h  = (u16*)(ws + 413696);
  u16*   x_l  = (u16*)(ws + 618496);
  float* qkvbuf = ws + 823296;
  float* aopart = ws + 823296;
  u16*   relu_h = (u16*)(ws + 823296);
  u16*   relu_l = (u16*)(ws + 1642496);
  float* Af     = ws + 823296;
  float* Bm     = ws + 1232896;
  float* pO_buf = ws + 2461696;
  float* f2part = ws + 2461696;
  float* pl_buf = ws + 4100096;
  u16*   WH   = (u16*)(ws + 4151296);
  u16*   WL   = (u16*)(ws + 5396480);
  int*   bar  = (int*)(ws + 6641664);

  const u32 QO = 0, AOO = 589824, F1O = 786432, F2O = 1572864,
            WAO = 2359296, WBO = 2424832;

  int tid = threadIdx.x;
  int lane = tid & 63, wv = tid >> 6;
  int bid = blockIdx.x;
  int bcnt = 0;

  __shared__ union {
    float s[Hd];
    float hs[NDd];
    struct { float Ks[50][32]; float Vs[50][32]; } at;
    struct { float ps[4]; float ps2[4]; } ln;
  } sm;

  // ---------------- P0: temb + uw0 + weight split ----------------
  if (bid < 8) {
    int b = bid;
    float pre = t[b] * tw1[tid] + tb1[tid];
    sm.s[tid] = siluf(pre);
    __syncthreads();
    float acc = tb2[tid];
#pragma unroll 8
    for (int k = 0; k < Hd; ++k) acc += sm.s[k] * tw2[k * Hd + tid];
    temb[b * Hd + tid] = acc;
  } else if (bid == 8) {
    int c = tid;
    const float* wcp = ow1 + 2 * Hd * Hd;
    float uu = 0.f, wwv = 0.f;
    for (int hh = 0; hh < Hd; ++hh) {
      float w = wcp[hh * Hd + c];
      uu += ew[hh] * w;
      wwv += eb[hh] * w;
    }
    u[c] = uu;
    w0[c] = wwv + ob1[c];
  }
  {
    int TOT = sa.pre[14];
    for (int base = bid * 256; base < TOT; base += GRD * 256) {
      int g = base + tid;
      if (g < TOT) {
        int d = 0;
        while (g >= sa.pre[d + 1]) ++d;
        int idx = g - sa.pre[d];
        SplitDesc dd = sa.d[d];
        int n = idx % dd.N;
        int kq = idx / dd.N;
        int ks = kq >> 2, q = kq & 3;
        int KS = dd.K >> 5;
        short8 vh, vl;
#pragma unroll
        for (int kr = 0; kr < 8; ++kr) {
          float v = dd.s[(size_t)(ks * 32 + q * 8 + kr) * dd.N + n];
          u16 hh, ll;
          bsplit(v, hh, ll);
          vh[kr] = (short)hh;
          vl[kr] = (short)ll;
        }
        u32 o = (((u32)(n >> 4) * KS + ks) * 64 + q * 16 + (n & 15)) * 8 + dd.off;
        *(short8*)(WH + o) = vh;
        *(short8*)(WL + o) = vl;
      }
    }
  }
  gbar(bar, bcnt++);

  // ---------------- proj ----------------
  for (int m = bid; m < Mtot; m += GRD) {
    int b = m / Nn;
    if (tid < NDd) sm.hs[tid] = hin[(size_t)m * NDd + tid];
    __syncthreads();
    float acc = pb[tid] + temb[b * Hd + tid];
#pragma unroll 8
    for (int k = 0; k < NDd; ++k) acc += sm.hs[k] * pw[k * Hd + tid];
    x[(size_t)m * Hd + tid] = acc;
    store_xfrag(x_h, x_l, m, tid, acc);
    __syncthreads();
  }
  gbar(bar, bcnt++);

  // ---------------- layers ----------------
  for (int l = 0; l < Ld; ++l) {
    // qkv: 300 tiles (25 x 12)
    for (int tl = bid; tl < 300; tl += GRD)
      gemm_tile<8, 0, 0>(tl % 25, tl / 25, 0, lane, wv, x_h, x_l, nullptr,
                         nullptr, WH + QO + (u32)l * 196608,
                         WL + QO + (u32)l * 196608, qkv_b + l * 3 * Hd, qkvbuf,
                         nullptr, nullptr, 3 * Hd, 8, 0);
    gbar(bar, bcnt++);

    // attn: 256 tiles (4 jq x 8 heads x 8 batch)
    for (int tl = bid; tl < 256; tl += GRD) {
      int jq = tl & 3, hd = (tl >> 2) & 7, b = tl >> 5;
      for (int idx = tid; idx < 400; idx += 256) {
        int row = idx >> 3, c4 = (idx & 7) * 4;
        const float* src = qkvbuf +
            ((size_t)(b * Nn + jq * 50 + row)) * (3 * Hd) + Hd + hd * DHd + c4;
        *(float4*)&sm.at.Ks[row][c4] = *(const float4*)src;
        *(float4*)&sm.at.Vs[row][c4] = *(const float4*)(src + Hd);
      }
      __syncthreads();
      if (tid < Nn) {
        int i = tid;
        float q[32];
        const float* qrow = qkvbuf + ((size_t)(b * Nn + i)) * (3 * Hd) + hd * DHd;
#pragma unroll
        for (int c4 = 0; c4 < 32; c4 += 4)
          *(float4*)&q[c4] = *(const float4*)&qrow[c4];
        float O[32];
#pragma unroll
        for (int c = 0; c < 32; ++c) O[c] = 0.f;
        float lsum = 0.f;
#pragma unroll 2
        for (int j = 0; j < 50; ++j) {
          float kr[32], vr[32];
#pragma unroll
          for (int c4 = 0; c4 < 32; c4 += 4) {
            *(float4*)&kr[c4] = *(const float4*)&sm.at.Ks[j][c4];
            *(float4*)&vr[c4] = *(const float4*)&sm.at.Vs[j][c4];
          }
          float d = 0.f;
#pragma unroll
          for (int c = 0; c < 32; ++c) d += q[c] * kr[c];
          float p = __expf(d * 0.1767766952966369f);
          lsum += p;
#pragma unroll
          for (int c = 0; c < 32; ++c) O[c] += p * vr[c];
        }
        size_t base = (size_t)((b * NHh + hd) * 4 + jq) * Nn + i;
        pl_buf[base] = lsum;
        float* po = pO_buf + base * 32;
#pragma unroll
        for (int c4 = 0; c4 < 32; c4 += 4) *(float4*)&po[c4] = *(float4*)&O[c4];
      }
      __syncthreads();
    }
    gbar(bar, bcnt++);

    // ao + merge: 200 tiles (25 x 4 x 2), k-split partials
    for (int tl = bid; tl < 200; tl += GRD) {
      int t2 = tl / 25;
      gemm_tile<4, 0, 1>(tl % 25, t2 % 4, t2 / 4, lane, wv, nullptr, nullptr,
                         pO_buf, pl_buf, WH + AOO + (u32)l * 65536,
                         WL + AOO + (u32)l * 65536, nullptr, aopart, nullptr,
                         nullptr, Hd, 8, ZS);
    }
    gbar(bar, bcnt++);

    // ln1: 1600 rows
    for (int m = bid; m < Mtot; m += GRD) {
      float v = x[(size_t)m * Hd + tid] + ao_b[l * Hd + tid];
      for (int z = 0; z < 2; ++z) v += aopart[(size_t)z * ZS + m * Hd + tid];
      float s = v, s2 = v * v;
      for (int off = 32; off; off >>= 1) {
        s += __shfl_down(s, off);
        s2 += __shfl_down(s2, off);
      }
      if (!lane) { sm.ln.ps[wv] = s; sm.ln.ps2[wv] = s2; }
      __syncthreads();
      float mean = (sm.ln.ps[0] + sm.ln.ps[1] + sm.ln.ps[2] + sm.ln.ps[3]) * (1.0f / Hd);
      float msq = (sm.ln.ps2[0] + sm.ln.ps2[1] + sm.ln.ps2[2] + sm.ln.ps2[3]) * (1.0f / Hd);
      float inv = rsqrtf(msq - mean * mean + 1e-5f);
      float o = (v - mean) * inv * ln1_g[l * Hd + tid] + ln1_b[l * Hd + tid];
      x[(size_t)m * Hd + tid] = o;
      store_xfrag(x_h, x_l, m, tid, o);
      __syncthreads();
    }
    gbar(bar, bcnt++);

    // f1: 400 tiles (25 x 16), relu -> frags
    for (int tl = bid; tl < 400; tl += GRD)
      gemm_tile<8, 1, 0>(tl % 25, tl / 25, 0, lane, wv, x_h, x_l, nullptr,
                         nullptr, WH + F1O + (u32)l * 262144,
                         WL + F1O + (u32)l * 262144, f1_b + l * FFd, nullptr,
                         relu_h, relu_l, FFd, 8, 0);
    gbar(bar, bcnt++);

    // f2: 400 tiles (25 x 4 x 4), k-split partials
    for (int tl = bid; tl < 400; tl += GRD) {
      int t2 = tl / 25;
      gemm_tile<8, 0, 0>(tl % 25, t2 % 4, t2 / 4, lane, wv, relu_h, relu_l,
                         nullptr, nullptr, WH + F2O + (u32)l * 262144,
                         WL + F2O + (u32)l * 262144, nullptr, f2part, nullptr,
                         nullptr, Hd, 32, ZS);
    }
    gbar(bar, bcnt++);

    // ln2: 1600 rows
    for (int m = bid; m < Mtot; m += GRD) {
      float v = x[(size_t)m * Hd + tid] + f2_b[l * Hd + tid];
      for (int z = 0; z < 4; ++z) v += f2part[(size_t)z * ZS + m * Hd + tid];
      float s = v, s2 = v * v;
      for (int off = 32; off; off >>= 1) {
        s += __shfl_down(s, off);
        s2 += __shfl_down(s2, off);
      }
      if (!lane) { sm.ln.ps[wv] = s; sm.ln.ps2[wv] = s2; }
      __syncthreads();
      float mean = (sm.ln.ps[0] + sm.ln.ps[1] + sm.ln.ps[2] + sm.ln.ps[3]) * (1.0f / Hd);
      float msq = (sm.ln.ps2[0] + sm.ln.ps2[1] + sm.ln.ps2[2] + sm.ln.ps2[3]) * (1.0f / Hd);
      float inv = rsqrtf(msq - mean * mean + 1e-5f);
      float o = (v - mean) * inv * ln2_g[l * Hd + tid] + ln2_b[l * Hd + tid];
      x[(size_t)m * Hd + tid] = o;
      store_xfrag(x_h, x_l, m, tid, o);
      __syncthreads();
    }
    gbar(bar, bcnt++);
  }

  // ---------------- Af/Bm: 200 tiles (25 x 8) ----------------
  for (int tl = bid; tl < 200; tl += GRD) {
    int by = tl / 25;
    int sel = by >> 2;
    gemm_tile<8, 0, 0>(tl % 25, by & 3, 0, lane, wv, x_h, x_l, nullptr,
                       nullptr, sel ? WH + WBO : WH + WAO,
                       sel ? WL + WBO : WL + WAO, sel ? nullptr : w0,
                       sel ? Bm : Af, nullptr, nullptr, Hd, 8, 0);
  }
  gbar(bar, bcnt++);

  // ---------------- final: 2000 tiles x 4 waves ----------------
  {
    int cg = lane & 31, jp = lane >> 5;
    float u8[8], w2[16];
    *(float4*)&u8[0] = *(const float4*)&u[cg * 8];
    *(float4*)&u8[4] = *(const float4*)&u[cg * 8 + 4];
#pragma unroll
    for (int q = 0; q < 4; ++q)
      *(float4*)&w2[q * 4] = *(const float4*)&ow2[cg * 16 + q * 4];
    float ob20 = ob2[0], ob21 = ob2[1];
    for (int tl = bid; tl < 2000; tl += GRD) {
      int gw = tl * 4 + wv;  // 0..7999
      int bi2 = gw / 5;
      int jq = gw - bi2 * 5;
      int b = bi2 / Nn;
      float ar[8];
      const float* arp = Af + (size_t)bi2 * Hd + cg * 8;
      *(float4*)&ar[0] = *(const float4*)&arp[0];
      *(float4*)&ar[4] = *(const float4*)&arp[4];
      const float* xtrow = xt + (size_t)bi2 * Nn;
      const float* bmb = Bm + (size_t)(b * Nn) * Hd + cg * 8;
      for (int tt = 0; tt < 10; ++tt) {
        int j0 = jq * 40 + tt * 4;
        int jA = j0 + jp, jB = j0 + 2 + jp;
        float brA[8], brB[8];
        const float* pA = bmb + (size_t)jA * Hd;
        const float* pB = bmb + (size_t)jB * Hd;
        *(float4*)&brA[0] = *(const float4*)&pA[0];
        *(float4*)&brA[4] = *(const float4*)&pA[4];
        *(float4*)&brB[0] = *(const float4*)&pB[0];
        *(float4*)&brB[4] = *(const float4*)&pB[4];
        float xA = xtrow[jA], xB = xtrow[jB];
        float a0 = 0.f, a1 = 0.f, c0 = 0.f, c1 = 0.f;
#pragma unroll
        for (int c = 0; c < 8; ++c) {
          float preA = ar[c] + brA[c] + xA * u8[c];
          float sA = siluf(preA);
          a0 += sA * w2[2 * c];
          a1 += sA * w2[2 * c + 1];
          float preB = ar[c] + brB[c] + xB * u8[c];
          float sB = siluf(preB);
          c0 += sB * w2[2 * c];
          c1 += sB * w2[2 * c + 1];
        }
#pragma unroll
        for (int m = 1; m < 32; m <<= 1) {
          a0 += __shfl_xor(a0, m);
          a1 += __shfl_xor(a1, m);
          c0 += __shfl_xor(c0, m);
          c1 += __shfl_xor(c1, m);
        }
        if (cg == 0) {
          size_t pa = ((size_t)bi2 * Nn + jA) * 2;
          out[pa] = a0 + ob20;
          out[pa + 1] = a1 + ob21;
          size_t pb2 = ((size_t)bi2 * Nn + jB) * 2;
          out[pb2] = c0 + ob20;
          out[pb2 + 1] = c1 + ob21;
        }
      }
    }
  }
}

extern "C" void kernel_launch(void* const* d_in, const int* in_sizes, int n_in,
                              void* d_out, int out_size, void* d_ws, size_t ws_size,
                              hipStream_t stream) {
  const float* h   = (const float*)d_in[0];
  const float* xt  = (const float*)d_in[1];
  const float* t   = (const float*)d_in[2];
  const float* tw1 = (const float*)d_in[3];
  const float* tb1 = (const float*)d_in[4];
  const float* tw2 = (const float*)d_in[5];
  const float* tb2 = (const float*)d_in[6];
  const float* ew  = (const float*)d_in[7];
  const float* eb  = (const float*)d_in[8];
  const float* pw  = (const float*)d_in[9];
  const float* pb  = (const float*)d_in[10];
  const float* qkv_w = (const float*)d_in[11];
  const float* qkv_b = (const float*)d_in[12];
  const float* ao_w  = (const float*)d_in[13];
  const float* ao_b  = (const float*)d_in[14];
  const float* ln1_g = (const float*)d_in[15];
  const float* ln1_b = (const float*)d_in[16];
  const float* f1_w  = (const float*)d_in[17];
  const float* f1_b  = (const float*)d_in[18];
  const float* f2_w  = (const float*)d_in[19];
  const float* f2_b  = (const float*)d_in[20];
  const float* ln2_g = (const float*)d_in[21];
  const float* ln2_b = (const float*)d_in[22];
  const float* ow1   = (const float*)d_in[23];
  const float* ob1   = (const float*)d_in[24];
  const float* ow2   = (const float*)d_in[25];
  const float* ob2   = (const float*)d_in[26];
  float* out = (float*)d_out;
  float* ws = (float*)d_ws;

  const u32 QO = 0, AOO = 589824, F1O = 786432, F2O = 1572864,
            WAO = 2359296, WBO = 2424832;

  SplitArgs sa;
  for (int l = 0; l < Ld; ++l) {
    sa.d[l * 4 + 0] = {qkv_w + (size_t)l * 196608, QO + (u32)l * 196608, 256, 768};
    sa.d[l * 4 + 1] = {ao_w + (size_t)l * 65536, AOO + (u32)l * 65536, 256, 256};
    sa.d[l * 4 + 2] = {f1_w + (size_t)l * 262144, F1O + (u32)l * 262144, 256, 1024};
    sa.d[l * 4 + 3] = {f2_w + (size_t)l * 262144, F2O + (u32)l * 262144, 1024, 256};
  }
  sa.d[12] = {ow1, WAO, 256, 256};
  sa.d[13] = {ow1 + 65536, WBO, 256, 256};
  int acc = 0;
  for (int i = 0; i < 14; ++i) {
    sa.pre[i] = acc;
    acc += sa.d[i].K * sa.d[i].N / 8;
  }
  sa.pre[14] = acc;  // 311296

  int* bar = (int*)(ws + 6641664);
  hipMemsetAsync(bar, 0, NBAR * sizeof(int), stream);
  mega_kernel<<<GRD, 256, 0, stream>>>(
      sa, ws, h, xt, t, tw1, tb1, tw2, tb2, ew, eb, pw, pb, qkv_b, ao_b,
      ln1_g, ln1_b, f1_b, f2_b, ln2_g, ln2_b, ow1, ob1, ow2, ob2, out);
}

// Round 10
// 353.477 us; speedup vs baseline: 5.3909x; 5.3909x over previous
//
#include <hip/hip_runtime.h>

#define Bdim 8
#define Nn 200
#define NDd 128
#define Hd 256
#define FFd 1024
#define Ld 3
#define NHh 8
#define DHd 32
#define Mtot (Bdim * Nn)  // 1600
#define ZS 409600         // partial stride (Mtot*Hd)
#define LNS 260           // padded LDS row stride (floats)

typedef unsigned short u16;
typedef unsigned int u32;
using short8 = __attribute__((ext_vector_type(8))) short;
using fx4 = __attribute__((ext_vector_type(4))) float;

__device__ __forceinline__ float siluf(float x) {
  return x * __builtin_amdgcn_rcpf(1.0f + __expf(-x));
}

__device__ __forceinline__ void bsplit(float x, u16& h, u16& l) {
  u32 b = __float_as_uint(x);
  h = (u16)(b >> 16);
  float hf = __uint_as_float(b & 0xffff0000u);
  float r = x - hf;
  l = (u16)(__float_as_uint(r) >> 16);
}

__device__ __forceinline__ void store_xfrag(u16* __restrict__ xh,
                                            u16* __restrict__ xl, int m, int c,
                                            float v) {
  u32 o = ((u32)((m >> 4) * 8 + (c >> 5)) * 64 + ((c & 31) >> 3) * 16 +
           (m & 15)) * 8 + (c & 7);
  u16 hh, ll;
  bsplit(v, hh, ll);
  xh[o] = hh;
  xl[o] = ll;
}

// ---------------- prep: weight split + temb + uw0 ----------------
struct SplitDesc {
  const float* s;
  u32 off;
  int K, N;
};
struct SplitArgs {
  SplitDesc d[14];
};

__global__ __launch_bounds__(256) void prep_kernel(
    SplitArgs a, u16* __restrict__ WH, u16* __restrict__ WL,
    const float* __restrict__ t, const float* __restrict__ tw1,
    const float* __restrict__ tb1, const float* __restrict__ tw2,
    const float* __restrict__ tb2, float* __restrict__ temb,
    const float* __restrict__ ew, const float* __restrict__ eb,
    const float* __restrict__ ow1, const float* __restrict__ ob1,
    float* __restrict__ u, float* __restrict__ w0) {
  __shared__ float s[Hd];
  if (blockIdx.y < 14) {
    SplitDesc dd = a.d[blockIdx.y];
    int idx = blockIdx.x * 256 + threadIdx.x;
    int total8 = dd.K * dd.N / 8;
    if (idx >= total8) return;
    int n = idx % dd.N;
    int kq = idx / dd.N;
    int ks = kq >> 2, q = kq & 3;
    int KS = dd.K >> 5;
    short8 vh, vl;
#pragma unroll
    for (int kr = 0; kr < 8; ++kr) {
      float v = dd.s[(size_t)(ks * 32 + q * 8 + kr) * dd.N + n];
      u16 hh, ll;
      bsplit(v, hh, ll);
      vh[kr] = (short)hh;
      vl[kr] = (short)ll;
    }
    u32 o = (((u32)(n >> 4) * KS + ks) * 64 + q * 16 + (n & 15)) * 8 + dd.off;
    *(short8*)(WH + o) = vh;
    *(short8*)(WL + o) = vl;
  } else {
    if (blockIdx.x < 8) {
      int b = blockIdx.x, h = threadIdx.x;
      float pre = t[b] * tw1[h] + tb1[h];
      s[h] = siluf(pre);
      __syncthreads();
      float acc = tb2[h];
#pragma unroll 8
      for (int k = 0; k < Hd; ++k) acc += s[k] * tw2[k * Hd + h];
      temb[b * Hd + h] = acc;
    } else if (blockIdx.x == 8) {
      int c = threadIdx.x;
      const float* wcp = ow1 + 2 * Hd * Hd;
      float uu = 0.f, ww = 0.f;
      for (int hh = 0; hh < Hd; ++hh) {
        float wv = wcp[hh * Hd + c];
        uu += ew[hh] * wv;
        ww += eb[hh] * wv;
      }
      u[c] = uu;
      w0[c] = ww + ob1[c];
    }
  }
}

// x = h @ pw + pb + temb[b]; also emits x A-fragments (for qkv l0)
__global__ __launch_bounds__(256) void proj_kernel(
    const float* __restrict__ h, const float* __restrict__ pw,
    const float* __restrict__ pb, const float* __restrict__ temb,
    float* __restrict__ x, u16* __restrict__ xh, u16* __restrict__ xl) {
  int m = blockIdx.x, n = threadIdx.x, b = m / Nn;
  __shared__ float hs[NDd];
  if (n < NDd) hs[n] = h[m * NDd + n];
  __syncthreads();
  float acc = pb[n] + temb[b * Hd + n];
#pragma unroll 8
  for (int k = 0; k < NDd; ++k) acc += hs[k] * pw[k * Hd + n];
  x[m * Hd + n] = acc;
  store_xfrag(xh, xl, m, n, acc);
}

// ---------------- plain bf16x3 MFMA GEMM (qkv l0, ao+merge, f2) ----------
template <int KSZ, int EPI, int MERGE>
__global__ __launch_bounds__(256) void mfma_gemm(
    const u16* __restrict__ ah, const u16* __restrict__ al,
    const float* __restrict__ pO, const float* __restrict__ pl,
    const u16* __restrict__ wh, const u16* __restrict__ wl,
    const float* __restrict__ bias, float* __restrict__ outf,
    u16* __restrict__ oh, u16* __restrict__ ol, int N, int KS,
    size_t zstride) {
  int lane = threadIdx.x & 63, wv = threadIdx.x >> 6;
  int rt = blockIdx.x * 4 + wv;
  int nt0 = blockIdx.y * 4;
  int ks0 = blockIdx.z * KSZ;
  int m16 = lane & 15, quad = lane >> 4;
  int mrow = rt * 16 + m16;
  int bq = mrow / Nn, iq = mrow % Nn;
  fx4 z4 = {0.f, 0.f, 0.f, 0.f};
  fx4 acc[4] = {z4, z4, z4, z4};
  const short8* pah = (const short8*)ah;
  const short8* pal = (const short8*)al;
  const short8* pwh = (const short8*)wh;
  const short8* pwl = (const short8*)wl;

  auto loadA = [&](int ks, short8& a_h, short8& a_l) {
    if (MERGE) {
      int head = ks0 + ks;
      float o8[8];
      float denom = 0.f;
#pragma unroll
      for (int z = 0; z < 4; ++z) {
        int base = ((bq * NHh + head) * 4 + z) * Nn + iq;
        denom += pl[base];
        const float* p = pO + (size_t)base * 32 + quad * 8;
        float4 v0 = *(const float4*)p;
        float4 v1 = *(const float4*)(p + 4);
        if (z == 0) {
          o8[0] = v0.x; o8[1] = v0.y; o8[2] = v0.z; o8[3] = v0.w;
          o8[4] = v1.x; o8[5] = v1.y; o8[6] = v1.z; o8[7] = v1.w;
        } else {
          o8[0] += v0.x; o8[1] += v0.y; o8[2] += v0.z; o8[3] += v0.w;
          o8[4] += v1.x; o8[5] += v1.y; o8[6] += v1.z; o8[7] += v1.w;
        }
      }
      float rd = 1.0f / denom;
#pragma unroll
      for (int e = 0; e < 8; ++e) {
        u16 hh, ll;
        bsplit(o8[e] * rd, hh, ll);
        a_h[e] = (short)hh;
        a_l[e] = (short)ll;
      }
    } else {
      a_h = pah[(size_t)(rt * KS + ks0 + ks) * 64 + lane];
      a_l = pal[(size_t)(rt * KS + ks0 + ks) * 64 + lane];
    }
  };

  short8 ca_h, ca_l, cb_h[4], cb_l[4];
  loadA(0, ca_h, ca_l);
#pragma unroll
  for (int nt = 0; nt < 4; ++nt) {
    size_t wi = ((size_t)(nt0 + nt) * KS + ks0) * 64 + lane;
    cb_h[nt] = pwh[wi];
    cb_l[nt] = pwl[wi];
  }
#pragma unroll
  for (int ks = 0; ks < KSZ; ++ks) {
    short8 na_h, na_l, nb_h[4], nb_l[4];
    if (ks + 1 < KSZ) {
      loadA(ks + 1, na_h, na_l);
#pragma unroll
      for (int nt = 0; nt < 4; ++nt) {
        size_t wi = ((size_t)(nt0 + nt) * KS + ks0 + ks + 1) * 64 + lane;
        nb_h[nt] = pwh[wi];
        nb_l[nt] = pwl[wi];
      }
    }
#pragma unroll
    for (int nt = 0; nt < 4; ++nt) {
      acc[nt] = __builtin_amdgcn_mfma_f32_16x16x32_bf16(ca_h, cb_h[nt], acc[nt], 0, 0, 0);
      acc[nt] = __builtin_amdgcn_mfma_f32_16x16x32_bf16(ca_h, cb_l[nt], acc[nt], 0, 0, 0);
      acc[nt] = __builtin_amdgcn_mfma_f32_16x16x32_bf16(ca_l, cb_h[nt], acc[nt], 0, 0, 0);
    }
    ca_h = na_h;
    ca_l = na_l;
#pragma unroll
    for (int nt = 0; nt < 4; ++nt) {
      cb_h[nt] = nb_h[nt];
      cb_l[nt] = nb_l[nt];
    }
  }

  size_t zoff = (size_t)blockIdx.z * zstride;
#pragma unroll
  for (int nt = 0; nt < 4; ++nt) {
    int col = (nt0 + nt) * 16 + m16;
    float bv = (bias && blockIdx.z == 0) ? bias[col] : 0.f;
#pragma unroll
    for (int r = 0; r < 4; ++r) {
      int row = rt * 16 + quad * 4 + r;
      float v = acc[nt][r] + bv;
      if (EPI == 0) {
        outf[zoff + (size_t)row * N + col] = v;
      } else {
        v = fmaxf(v, 0.f);
        u32 o = ((u32)(rt * 32 + (col >> 5)) * 64 + ((col & 31) >> 3) * 16 +
                 (row & 15)) * 8 + (col & 7);
        u16 hh, ll;
        bsplit(v, hh, ll);
        oh[o] = hh;
        ol[o] = ll;
      }
    }
  }
}

// ------- fused consumer GEMM: LN(xin + sum parts + rbias) -> A, then GEMM --
// Block = 16 rows x 256 cols: grid (100, Ngroups). 4 waves x 4 n-tiles.
// by==0 blocks write the LN'd fp32 residual stream to xout.
// EPI=0: outf[row*N+col] + bias[col]; EPI=1: relu -> A-frag bf16 (K=1024).
// BSEL=1 (afbm): by selects weights (+wsel u16) and out buffer (+osel),
//                bias (w0) applied only for by==0; n-groups collapse to 1.
template <int NPARTS, int EPI, int BSEL>
__global__ __launch_bounds__(256) void gemm_lnfold(
    const float* __restrict__ xin, const float* __restrict__ parts,
    const float* __restrict__ rbias, const float* __restrict__ g,
    const float* __restrict__ bb, float* __restrict__ xout,
    const u16* __restrict__ wh, const u16* __restrict__ wl,
    const float* __restrict__ bias, float* __restrict__ outf,
    u16* __restrict__ oh, u16* __restrict__ ol, int N,
    int wsel, size_t osel) {
  __shared__ float lnt[16][LNS];
  int tid = threadIdx.x;
  int lane = tid & 63, wv = tid >> 6;
  int strip = blockIdx.x, by = blockIdx.y;

  // ---- phase 1: LN of rows strip*16..+15 ----
  {
    int row = tid >> 4;
    int c0 = (tid & 15) * 16;
    int grow = strip * 16 + row;
    float v[16];
    const float* xr = xin + (size_t)grow * Hd + c0;
#pragma unroll
    for (int e = 0; e < 16; e += 4) {
      float4 xv = *(const float4*)(xr + e);
      v[e] = xv.x; v[e + 1] = xv.y; v[e + 2] = xv.z; v[e + 3] = xv.w;
    }
#pragma unroll
    for (int z = 0; z < NPARTS; ++z) {
      const float* pr = parts + (size_t)z * ZS + (size_t)grow * Hd + c0;
#pragma unroll
      for (int e = 0; e < 16; e += 4) {
        float4 pv = *(const float4*)(pr + e);
        v[e] += pv.x; v[e + 1] += pv.y; v[e + 2] += pv.z; v[e + 3] += pv.w;
      }
    }
    float s = 0.f, s2 = 0.f;
#pragma unroll
    for (int e = 0; e < 16; e += 4) {
      float4 bv = *(const float4*)(rbias + c0 + e);
      v[e] += bv.x; v[e + 1] += bv.y; v[e + 2] += bv.z; v[e + 3] += bv.w;
#pragma unroll
      for (int q = 0; q < 4; ++q) { s += v[e + q]; s2 += v[e + q] * v[e + q]; }
    }
#pragma unroll
    for (int m = 1; m < 16; m <<= 1) {
      s += __shfl_xor(s, m);
      s2 += __shfl_xor(s2, m);
    }
    float mean = s * (1.0f / Hd);
    float inv = rsqrtf(s2 * (1.0f / Hd) - mean * mean + 1e-5f);
#pragma unroll
    for (int e = 0; e < 16; e += 4) {
      float4 gv = *(const float4*)(g + c0 + e);
      float4 bbv = *(const float4*)(bb + c0 + e);
      v[e] = (v[e] - mean) * inv * gv.x + bbv.x;
      v[e + 1] = (v[e + 1] - mean) * inv * gv.y + bbv.y;
      v[e + 2] = (v[e + 2] - mean) * inv * gv.z + bbv.z;
      v[e + 3] = (v[e + 3] - mean) * inv * gv.w + bbv.w;
      *(float4*)&lnt[row][c0 + e] = *(float4*)&v[e];
    }
    if (xout && by == 0) {
      float* xo = xout + (size_t)grow * Hd + c0;
#pragma unroll
      for (int e = 0; e < 16; e += 4) *(float4*)(xo + e) = *(float4*)&v[e];
    }
  }
  __syncthreads();

  // ---- phase 2: GEMM, A from LDS ----
  int m16 = lane & 15, quad = lane >> 4;
  const short8* pwh = (const short8*)(BSEL ? wh + (size_t)by * wsel : wh);
  const short8* pwl = (const short8*)(BSEL ? wl + (size_t)by * wsel : wl);
  int ntbase = BSEL ? (wv * 4) : (by * 16 + wv * 4);
  fx4 z4 = {0.f, 0.f, 0.f, 0.f};
  fx4 acc[4] = {z4, z4, z4, z4};
#pragma unroll 2
  for (int ks = 0; ks < 8; ++ks) {
    short8 a_h, a_l;
    float4 a0 = *(const float4*)&lnt[m16][ks * 32 + quad * 8];
    float4 a1 = *(const float4*)&lnt[m16][ks * 32 + quad * 8 + 4];
    float av[8] = {a0.x, a0.y, a0.z, a0.w, a1.x, a1.y, a1.z, a1.w};
#pragma unroll
    for (int e = 0; e < 8; ++e) {
      u16 hh, ll;
      bsplit(av[e], hh, ll);
      a_h[e] = (short)hh;
      a_l[e] = (short)ll;
    }
#pragma unroll
    for (int nt = 0; nt < 4; ++nt) {
      size_t wi = ((size_t)(ntbase + nt) * 8 + ks) * 64 + lane;
      short8 b_h = pwh[wi];
      short8 b_l = pwl[wi];
      acc[nt] = __builtin_amdgcn_mfma_f32_16x16x32_bf16(a_h, b_h, acc[nt], 0, 0, 0);
      acc[nt] = __builtin_amdgcn_mfma_f32_16x16x32_bf16(a_h, b_l, acc[nt], 0, 0, 0);
      acc[nt] = __builtin_amdgcn_mfma_f32_16x16x32_bf16(a_l, b_h, acc[nt], 0, 0, 0);
    }
  }

  float* outp = BSEL ? outf + (size_t)by * osel : outf;
#pragma unroll
  for (int nt = 0; nt < 4; ++nt) {
    int col = (ntbase + nt) * 16 + m16;
    float bv = 0.f;
    if (bias) {
      if (BSEL) {
        if (by == 0) bv = bias[col];
      } else {
        bv = bias[col];
      }
    }
#pragma unroll
    for (int r = 0; r < 4; ++r) {
      int row = strip * 16 + quad * 4 + r;
      float v = acc[nt][r] + bv;
      if (EPI == 0) {
        outp[(size_t)row * N + col] = v;
      } else {
        v = fmaxf(v, 0.f);
        u32 o = ((u32)(strip * 32 + (col >> 5)) * 64 + ((col & 31) >> 3) * 16 +
                 (row & 15)) * 8 + (col & 7);
        u16 hh, ll;
        bsplit(v, hh, ll);
        oh[o] = hh;
        ol[o] = ll;
      }
    }
  }
}

// ---------------- flash attention, j-split x4 ----------------
__global__ __launch_bounds__(256) void attn_flash(
    const float* __restrict__ qkv, float* __restrict__ pO,
    float* __restrict__ pl) {
  int jq = blockIdx.x, hd = blockIdx.y, b = blockIdx.z;
  int tid = threadIdx.x;
  __shared__ float Ks[50][32], Vs[50][32];
  for (int idx = tid; idx < 400; idx += 256) {
    int row = idx >> 3, c4 = (idx & 7) * 4;
    const float* src =
        qkv + ((size_t)(b * Nn + jq * 50 + row)) * (3 * Hd) + Hd + hd * DHd + c4;
    *(float4*)&Ks[row][c4] = *(const float4*)src;
    *(float4*)&Vs[row][c4] = *(const float4*)(src + Hd);
  }
  __syncthreads();
  if (tid >= Nn) return;
  int i = tid;
  float q[32];
  const float* qrow = qkv + ((size_t)(b * Nn + i)) * (3 * Hd) + hd * DHd;
#pragma unroll
  for (int c4 = 0; c4 < 32; c4 += 4)
    *(float4*)&q[c4] = *(const float4*)&qrow[c4];
  float O[32];
#pragma unroll
  for (int c = 0; c < 32; ++c) O[c] = 0.f;
  float l = 0.f;
#pragma unroll 2
  for (int j = 0; j < 50; ++j) {
    float kr[32], vr[32];
#pragma unroll
    for (int c4 = 0; c4 < 32; c4 += 4) {
      *(float4*)&kr[c4] = *(const float4*)&Ks[j][c4];
      *(float4*)&vr[c4] = *(const float4*)&Vs[j][c4];
    }
    float d = 0.f;
#pragma unroll
    for (int c = 0; c < 32; ++c) d += q[c] * kr[c];
    float p = __expf(d * 0.1767766952966369f);
    l += p;
#pragma unroll
    for (int c = 0; c < 32; ++c) O[c] += p * vr[c];
  }
  size_t base = (size_t)((b * NHh + hd) * 4 + jq) * Nn + i;
  pl[base] = l;
  float* po = pO + base * 32;
#pragma unroll
  for (int c4 = 0; c4 < 32; c4 += 4) *(float4*)&po[c4] = *(float4*)&O[c4];
}

// out[b,i,j,:] = silu(Af[b,i]+Bm[b,j]+xt[b,i,j]*u) @ ow2 + ob2
__global__ __launch_bounds__(256) void final3_kernel(
    const float* __restrict__ Af, const float* __restrict__ Bm,
    const float* __restrict__ xt, const float* __restrict__ u,
    const float* __restrict__ ow2, const float* __restrict__ ob2,
    float* __restrict__ out) {
  int tid = threadIdx.x;
  int wid = tid >> 6, lane = tid & 63;
  int cg = lane & 31, jp = lane >> 5;
  int gw = blockIdx.x * 4 + wid;  // 0..7999
  int bi = gw / 5;
  int jq = gw - bi * 5;
  int b = bi / Nn;

  float u8[8], w2[16], ar[8];
  *(float4*)&u8[0] = *(const float4*)&u[cg * 8];
  *(float4*)&u8[4] = *(const float4*)&u[cg * 8 + 4];
#pragma unroll
  for (int q = 0; q < 4; ++q)
    *(float4*)&w2[q * 4] = *(const float4*)&ow2[cg * 16 + q * 4];
  const float* arp = Af + (size_t)bi * Hd + cg * 8;
  *(float4*)&ar[0] = *(const float4*)&arp[0];
  *(float4*)&ar[4] = *(const float4*)&arp[4];
  float ob20 = ob2[0], ob21 = ob2[1];

  const float* xtrow = xt + (size_t)bi * Nn;
  const float* bmb = Bm + (size_t)(b * Nn) * Hd + cg * 8;
  for (int t = 0; t < 10; ++t) {
    int j0 = jq * 40 + t * 4;
    int jA = j0 + jp, jB = j0 + 2 + jp;
    float brA[8], brB[8];
    const float* pA = bmb + (size_t)jA * Hd;
    const float* pB = bmb + (size_t)jB * Hd;
    *(float4*)&brA[0] = *(const float4*)&pA[0];
    *(float4*)&brA[4] = *(const float4*)&pA[4];
    *(float4*)&brB[0] = *(const float4*)&pB[0];
    *(float4*)&brB[4] = *(const float4*)&pB[4];
    float xA = xtrow[jA], xB = xtrow[jB];
    float a0 = 0.f, a1 = 0.f, c0 = 0.f, c1 = 0.f;
#pragma unroll
    for (int c = 0; c < 8; ++c) {
      float preA = ar[c] + brA[c] + xA * u8[c];
      float sA = siluf(preA);
      a0 += sA * w2[2 * c];
      a1 += sA * w2[2 * c + 1];
      float preB = ar[c] + brB[c] + xB * u8[c];
      float sB = siluf(preB);
      c0 += sB * w2[2 * c];
      c1 += sB * w2[2 * c + 1];
    }
#pragma unroll
    for (int m = 1; m < 32; m <<= 1) {
      a0 += __shfl_xor(a0, m);
      a1 += __shfl_xor(a1, m);
      c0 += __shfl_xor(c0, m);
      c1 += __shfl_xor(c1, m);
    }
    if (cg == 0) {
      size_t pa = ((size_t)bi * Nn + jA) * 2;
      out[pa] = a0 + ob20;
      out[pa + 1] = a1 + ob21;
      size_t pb = ((size_t)bi * Nn + jB) * 2;
      out[pb] = c0 + ob20;
      out[pb + 1] = c1 + ob21;
    }
  }
}

extern "C" void kernel_launch(void* const* d_in, const int* in_sizes, int n_in,
                              void* d_out, int out_size, void* d_ws, size_t ws_size,
                              hipStream_t stream) {
  const float* h   = (const float*)d_in[0];
  const float* xt  = (const float*)d_in[1];
  const float* t   = (const float*)d_in[2];
  const float* tw1 = (const float*)d_in[3];
  const float* tb1 = (const float*)d_in[4];
  const float* tw2 = (const float*)d_in[5];
  const float* tb2 = (const float*)d_in[6];
  const float* ew  = (const float*)d_in[7];
  const float* eb  = (const float*)d_in[8];
  const float* pw  = (const float*)d_in[9];
  const float* pb  = (const float*)d_in[10];
  const float* qkv_w = (const float*)d_in[11];
  const float* qkv_b = (const float*)d_in[12];
  const float* ao_w  = (const float*)d_in[13];
  const float* ao_b  = (const float*)d_in[14];
  const float* ln1_g = (const float*)d_in[15];
  const float* ln1_b = (const float*)d_in[16];
  const float* f1_w  = (const float*)d_in[17];
  const float* f1_b  = (const float*)d_in[18];
  const float* f2_w  = (const float*)d_in[19];
  const float* f2_b  = (const float*)d_in[20];
  const float* ln2_g = (const float*)d_in[21];
  const float* ln2_b = (const float*)d_in[22];
  const float* ow1   = (const float*)d_in[23];
  const float* ob1   = (const float*)d_in[24];
  const float* ow2   = (const float*)d_in[25];
  const float* ob2   = (const float*)d_in[26];
  float* out = (float*)d_out;

  float* ws = (float*)d_ws;
  // disjoint layout (no phase overlap; 43 MB of 268 MB ws)
  float* temb = ws;                    // 2048
  float* u    = ws + 2048;             // 256
  float* w0   = ws + 2304;             // 256
  float* xA   = ws + 4096;             // 409600
  u16*   x_h  = (u16*)(ws + 413696);   // 409600 u16
  u16*   x_l  = (u16*)(ws + 618496);
  float* xB   = ws + 823296;           // 409600
  float* qkvbuf = ws + 1232896;        // 1228800
  float* aopart = ws + 2461696;        // 819200 (2 partials)
  u16*   relu_h = (u16*)(ws + 3280896);// 1638400 u16
  u16*   relu_l = (u16*)(ws + 4100096);
  float* f2part = ws + 4919296;        // 1638400 (4 partials)
  float* pO_buf = ws + 6557696;        // 1638400
  float* pl_buf = ws + 8196096;        // 51200
  u16*   WH   = (u16*)(ws + 8247296);  // 2490368 u16
  u16*   WL   = (u16*)(ws + 9492480);  // 2490368 u16
  float* Af   = qkvbuf;                // reuse (dead by afbm)
  float* Bm   = qkvbuf + ZS;

  const u32 QO = 0, AOO = 589824, F1O = 786432, F2O = 1572864,
            WAO = 2359296, WBO = 2424832;

  SplitArgs sa;
  for (int l = 0; l < Ld; ++l) {
    sa.d[l * 4 + 0] = {qkv_w + (size_t)l * 196608, QO + (u32)l * 196608, 256, 768};
    sa.d[l * 4 + 1] = {ao_w + (size_t)l * 65536, AOO + (u32)l * 65536, 256, 256};
    sa.d[l * 4 + 2] = {f1_w + (size_t)l * 262144, F1O + (u32)l * 262144, 256, 1024};
    sa.d[l * 4 + 3] = {f2_w + (size_t)l * 262144, F2O + (u32)l * 262144, 1024, 256};
  }
  sa.d[12] = {ow1, WAO, 256, 256};
  sa.d[13] = {ow1 + 65536, WBO, 256, 256};

  prep_kernel<<<dim3(128, 15), 256, 0, stream>>>(
      sa, WH, WL, t, tw1, tb1, tw2, tb2, temb, ew, eb, ow1, ob1, u, w0);
  proj_kernel<<<Mtot, 256, 0, stream>>>(h, pw, pb, temb, xA, x_h, x_l);

  for (int l = 0; l < Ld; ++l) {
    if (l == 0) {
      // qkv l0: plain, reads proj frags
      mfma_gemm<8, 0, 0><<<dim3(25, 12, 1), 256, 0, stream>>>(
          x_h, x_l, nullptr, nullptr, WH + QO, WL + QO, qkv_b, qkvbuf,
          nullptr, nullptr, 3 * Hd, 8, 0);
    } else {
      // qkv l>=1 with folded ln2(l-1): reads xB + f2part, writes xA
      gemm_lnfold<4, 0, 0><<<dim3(100, 3), 256, 0, stream>>>(
          xB, f2part, f2_b + (l - 1) * Hd, ln2_g + (l - 1) * Hd,
          ln2_b + (l - 1) * Hd, xA, WH + QO + (u32)l * 196608,
          WL + QO + (u32)l * 196608, qkv_b + l * 3 * Hd, qkvbuf, nullptr,
          nullptr, 3 * Hd, 0, 0);
    }
    attn_flash<<<dim3(4, NHh, Bdim), 256, 0, stream>>>(qkvbuf, pO_buf, pl_buf);
    // ao + merge, k-split x2 -> aopart
    mfma_gemm<4, 0, 1><<<dim3(25, 4, 2), 256, 0, stream>>>(
        nullptr, nullptr, pO_buf, pl_buf, WH + AOO + (u32)l * 65536,
        WL + AOO + (u32)l * 65536, nullptr, aopart, nullptr, nullptr,
        Hd, 8, ZS);
    // f1 with folded ln1: reads xA + aopart, writes xB + relu frags
    gemm_lnfold<2, 1, 0><<<dim3(100, 4), 256, 0, stream>>>(
        xA, aopart, ao_b + l * Hd, ln1_g + l * Hd, ln1_b + l * Hd, xB,
        WH + F1O + (u32)l * 262144, WL + F1O + (u32)l * 262144,
        f1_b + l * FFd, nullptr, relu_h, relu_l, FFd, 0, 0);
    // f2: k-split x4 -> f2part
    mfma_gemm<8, 0, 0><<<dim3(25, 4, 4), 256, 0, stream>>>(
        relu_h, relu_l, nullptr, nullptr, WH + F2O + (u32)l * 262144,
        WL + F2O + (u32)l * 262144, nullptr, f2part, nullptr, nullptr,
        Hd, 32, ZS);
  }

  // Af/Bm with folded ln2(l2): reads xB + f2part; by selects wa/wb
  gemm_lnfold<4, 0, 1><<<dim3(100, 2), 256, 0, stream>>>(
      xB, f2part, f2_b + 2 * Hd, ln2_g + 2 * Hd, ln2_b + 2 * Hd, nullptr,
      WH + WAO, WL + WAO, w0, Af, nullptr, nullptr, Hd,
      (int)(WBO - WAO), (size_t)ZS);
  final3_kernel<<<2000, 256, 0, stream>>>(Af, Bm, xt, u, ow2, ob2, out);
}